// Round 11
// baseline (286.229 us; speedup 1.0000x reference)
//
#include <hip/hip_runtime.h>
#include <math.h>

#define BB 2
#define CC 256
#define NHEAD 8
#define HD 32
#define NGRP 8
#define NNTOK 32768
#define ATT_EPS 1e-6f
#define GN_EPS 1e-5f

typedef __attribute__((ext_vector_type(8))) short bfrag8;   // 8 bf16
typedef __attribute__((ext_vector_type(4))) float accf4;    // MFMA C/D 16x16

__device__ __forceinline__ float b2f(unsigned short u) {
    unsigned int x = ((unsigned int)u) << 16;
    return __uint_as_float(x);
}
__device__ __forceinline__ unsigned short f2b(float f) {
    unsigned int x = __float_as_uint(f);
    unsigned int r = x + 0x7fffu + ((x >> 16) & 1u);
    return (unsigned short)(r >> 16);
}
__device__ __forceinline__ void gl_lds16(const void* g, void* s) {
    __builtin_amdgcn_global_load_lds(
        (const __attribute__((address_space(1))) unsigned int*)g,
        (__attribute__((address_space(3))) unsigned int*)s, 16, 0, 0);
}

// ---- workspace layout (float offsets) ----
#define WS_QMT   0ull                      // bf16 [B][H][N][32]
#define WS_XNT   (WS_QMT + 8388608ull)     // bf16 [B][N][264] raw-x transpose
#define WS_WSTOLD (WS_XNT + 8650752ull)    // (old region, unused)
#define WS_PART  (WS_WSTOLD + 101632ull)   // big scratch region
#define WS_CTX2  WS_PART                   // f32 [16 bh][1056] atomic accumulators
#define WS_GNP2  (WS_PART + 135168ull)     // f32 [1024 blk][16] GN partials
#define WS_WST2  (WS_PART + 151552ull)     // bf16 [B*H][24576] folded W (frag-linear)
#define WS_BIAS  (WS_PART + 348160ull)     // f32 [B*H][96]
#define WS_GNPO  (WS_PART + 4325376ull)    // old chain (layout stability)
#define WS_SCALE (WS_GNPO + 2048ull)       // f32 [B][256]
#define WS_SHIFT (WS_SCALE + 512ull)       // f32 [B][256]
#define WS_CTXO  (WS_SHIFT + 512ull)
#define WS_KSUM  (WS_CTXO + 16384ull)      // f32 [B][H][32]
#define WS_AMAT  (WS_KSUM + 512ull)        // bf16 [B][256][256]

// LDS for qkv_ctx (29184 B): mainloop W chunk 24KB @0 (kc-half staged twice);
// epilogue overlay: kmv 64x272 @0, qs 128x80 @17408, ksp @27648; bias @28672
// (outside W chunk, persists). 160/29.2 -> 5 blocks/CU (was 3).
#define LDS_QS_OFF  17408
#define LDS_KSP_OFF 27648
#define LDS_BIAS_OFF 28672
#define LDS_QKV_TOTAL 29184

// ============ Kernel 1: fused x transpose->bf16 + GN partial sums (R10 verbatim) ============
__global__ __launch_bounds__(256) void xn_gn(const float* __restrict__ x,
                                             unsigned short* __restrict__ xn_t,
                                             float* __restrict__ gnp2) {
    __shared__ unsigned short xt[64][264];   // row = token, 528 B/row
    int b = blockIdx.y, n0 = blockIdx.x * 64, t = threadIdx.x;
    int g16 = t >> 4, ip = t & 15, col4 = ip * 4;
    float gs = 0.f, gs2 = 0.f;
    bfrag8 pk0, pk1, pk2, pk3;
    #pragma unroll
    for (int i = 0; i < 16; ++i) {
        int c = g16 * 16 + i;
        const float4 v = *(const float4*)(x + (size_t)(b * CC + c) * NNTOK + n0 + col4);
        gs  += v.x + v.y + v.z + v.w;
        gs2 += v.x * v.x + v.y * v.y + v.z * v.z + v.w * v.w;
        int k = i & 7;
        pk0[k] = (short)f2b(v.x);
        pk1[k] = (short)f2b(v.y);
        pk2[k] = (short)f2b(v.z);
        pk3[k] = (short)f2b(v.w);
        if (k == 7) {
            int cb = g16 * 32 + (i >> 3) * 16;   // byte offset of channel batch
            char* base = (char*)&xt[0][0] + cb;
            *(bfrag8*)(base + (col4 + 0) * 528) = pk0;
            *(bfrag8*)(base + (col4 + 1) * 528) = pk1;
            *(bfrag8*)(base + (col4 + 2) * 528) = pk2;
            *(bfrag8*)(base + (col4 + 3) * 528) = pk3;
        }
    }
    int lane = t & 63, w = t >> 6;
    #pragma unroll
    for (int off = 16; off; off >>= 1) {
        gs  += __shfl_down(gs, off);
        gs2 += __shfl_down(gs2, off);
    }
    if (lane == 0 || lane == 32) {
        int g = 2 * w + (lane >> 5);
        float* gp = gnp2 + (size_t)(b * 512 + blockIdx.x) * 16;
        gp[g * 2] = gs;
        gp[g * 2 + 1] = gs2;
    }
    __syncthreads();
    int n = t >> 2, q = t & 3;
    const char* src = (const char*)&xt[n][0] + q * 128;
    char* dst = (char*)(xn_t + ((size_t)b * NNTOK + n0 + n) * 264) + q * 128;
    #pragma unroll
    for (int i = 0; i < 8; ++i)
        *(float4*)(dst + i * 16) = *(const float4*)(src + i * 16);
}

// ============ Kernel 2: finalize GN stats -> scale/shift (R10 verbatim) ============
__global__ __launch_bounds__(256) void gn_stats2(const float* __restrict__ gnp2,
                                                 const float* __restrict__ gamma,
                                                 const float* __restrict__ beta,
                                                 float* __restrict__ scale,
                                                 float* __restrict__ shift) {
    __shared__ float red[256];
    __shared__ float mean_l[16], rstd_l[16];
    int t = threadIdx.x;
    int combo = t >> 3, sl = t & 7;      // combo = b2*16 + idx (idx = g*2+sel)
    int b2 = combo >> 4, idx = combo & 15;
    float a = 0.f;
    for (int k = sl; k < 512; k += 8)
        a += gnp2[(size_t)(b2 * 512 + k) * 16 + idx];
    red[t] = a;
    __syncthreads();
    if (t < 32) {
        float s = 0.f;
        #pragma unroll
        for (int j = 0; j < 8; ++j) s += red[t * 8 + j];
        red[t] = s;                      // stats[combo]
    }
    __syncthreads();
    if (t < 16) {
        const float inv = 1.0f / (float)((CC / NGRP) * NNTOK);
        float m = red[t * 2] * inv;
        float var = red[t * 2 + 1] * inv - m * m;
        mean_l[t] = m;
        rstd_l[t] = rsqrtf(var + GN_EPS);
    }
    __syncthreads();
    for (int i = t; i < BB * CC; i += 256) {
        int b = i >> 8, c = i & 255;
        int g = b * 8 + (c >> 5);
        float sc = gamma[c] * rstd_l[g];
        scale[i] = sc;
        shift[i] = beta[c] - mean_l[g] * sc;
    }
}

// ============ Kernel 3: fold scale into W + bias + distributed ctx2 zero (R10 verbatim) ============
__global__ __launch_bounds__(256) void fold_w(const float* __restrict__ wq,
                                              const float* __restrict__ wk,
                                              const float* __restrict__ wv,
                                              const float* __restrict__ scale,
                                              const float* __restrict__ shift,
                                              unsigned short* __restrict__ Wst2,
                                              float* __restrict__ bias,
                                              float* __restrict__ ctx2) {
    int slice = blockIdx.x, h = blockIdx.y, b2 = blockIdx.z, t = threadIdx.x;
    {
        int lin = slice + h * 8 + b2 * 64;   // 0..127
        int i = lin * 132 + t;
        if (t < 132) ctx2[i] = 0.f;
    }
    __shared__ float sc_l[256], sh_l[256];
    sc_l[t] = scale[b2 * CC + t];
    sh_l[t] = shift[b2 * CC + t];
    __syncthreads();
    const float* Ws[3] = {wq, wk, wv};
    unsigned short* wdst = Wst2 + (size_t)(b2 * NHEAD + h) * 24576;
    for (int i = slice * 3072 + t; i < (slice + 1) * 3072; i += 256) {
        int e = i & 7;
        int chunk = i >> 3;
        int lane = chunk & 63;
        int kcmi = chunk >> 6;
        int mi = kcmi % 6;
        int kc = kcmi / 6;
        int lr = lane & 15, lq = lane >> 4;
        int row = mi * 16 + lr;
        int col = kc * 32 + lq * 8 + e;
        float v = Ws[row >> 5][(size_t)(h * 32 + (row & 31)) * CC + col] * sc_l[col];
        wdst[i] = f2b(v);
    }
    if (t < 96) {
        int rl = t >> 3, sub = t & 7;
        int r = slice * 12 + rl;
        const float* wrow = Ws[r >> 5] + (size_t)(h * 32 + (r & 31)) * CC + sub * 32;
        float sp = 0.f;
        #pragma unroll
        for (int k = 0; k < 8; ++k) {
            const float4 v4 = *(const float4*)(wrow + k * 4);
            const float* shp = &sh_l[sub * 32 + k * 4];
            sp += v4.x * shp[0] + v4.y * shp[1] + v4.z * shp[2] + v4.w * shp[3];
        }
        sp += __shfl_xor(sp, 1);
        sp += __shfl_xor(sp, 2);
        sp += __shfl_xor(sp, 4);
        if (sub == 0) bias[(size_t)(b2 * NHEAD + h) * 96 + r] = sp;
    }
}

// ============ Kernel 4: fused QKV MFMA + bias + elu + ctx/ksum atomics ============
// R10 math; W staged in TWO 24KB kc-chunks into one buffer (+2 barriers) so
// the LDS high-water mark is the 29.2KB epilogue overlay -> 5 blocks/CU
// (20 waves, was 12). xn B-frags fully register-resident as before.
__global__ __launch_bounds__(256, 5) void qkv_ctx(
    const unsigned short* __restrict__ xn_t, const unsigned short* __restrict__ Wst2,
    const float* __restrict__ bias,
    unsigned short* __restrict__ qm_t, float* __restrict__ ctx2) {
    __shared__ char lds[LDS_QKV_TOTAL];
    const int id = blockIdx.x;
    const int xcd = id & 7;
    const int j = id >> 3;
    const int h = j & 7;
    const int rem = j >> 3;                 // 0..63
    const int tile = xcd * 32 + (rem & 31);
    const int b = rem >> 5;
    const int t = threadIdx.x;
    const int lane = t & 63, w = t >> 6;
    const int lr = lane & 15, lq = lane >> 4;
    const int n0 = tile * 128;

    const char* wg = (const char*)(Wst2 + (size_t)(b * NHEAD + h) * 24576);

    // stage W chunk A (kc 0..3, 24KB) + bias
    for (int jj = w; jj < 24; jj += 4)
        gl_lds16(wg + jj * 1024 + lane * 16, lds + jj * 1024);
    if (t < 96)
        ((float*)(lds + LDS_BIAS_OFF))[t] = bias[(size_t)(b * NHEAD + h) * 96 + t];

    // issue ALL xn fragment loads now — they complete during the stage drain
    const unsigned short* xr0 = xn_t + ((size_t)b * NNTOK + n0 + w * 32 + lr) * 264 + lq * 8;
    const unsigned short* xr1 = xr0 + 16 * 264;
    bfrag8 bnx[8][2];
    #pragma unroll
    for (int kc = 0; kc < 8; ++kc) {
        bnx[kc][0] = *(const bfrag8*)(xr0 + kc * 32);
        bnx[kc][1] = *(const bfrag8*)(xr1 + kc * 32);
    }
    __syncthreads();   // chunk A ready (drains all vmem)

    accf4 acc[6][2];
    #pragma unroll
    for (int i = 0; i < 6; ++i)
        #pragma unroll
        for (int jj = 0; jj < 2; ++jj) acc[i][jj] = (accf4){0.f, 0.f, 0.f, 0.f};

    const char* wl = lds;
    bfrag8 wnx[6];
    #pragma unroll
    for (int mi = 0; mi < 6; ++mi)
        wnx[mi] = *(const bfrag8*)(wl + (0 * 6 + mi) * 1024 + lane * 16);

    #pragma unroll
    for (int kc = 0; kc < 4; ++kc) {
        bfrag8 wcur[6];
        #pragma unroll
        for (int mi = 0; mi < 6; ++mi) wcur[mi] = wnx[mi];
        if (kc < 3) {
            #pragma unroll
            for (int mi = 0; mi < 6; ++mi)
                wnx[mi] = *(const bfrag8*)(wl + ((kc + 1) * 6 + mi) * 1024 + lane * 16);
        }
        #pragma unroll
        for (int mi = 0; mi < 6; ++mi)
            #pragma unroll
            for (int ci = 0; ci < 2; ++ci)
                acc[mi][ci] = __builtin_amdgcn_mfma_f32_16x16x32_bf16(wcur[mi], bnx[kc][ci], acc[mi][ci], 0, 0, 0);
    }
    __syncthreads();   // all waves done reading chunk A

    // stage W chunk B (kc 4..7) into the same buffer
    for (int jj = w; jj < 24; jj += 4)
        gl_lds16(wg + (24 + jj) * 1024 + lane * 16, lds + jj * 1024);
    __syncthreads();   // chunk B ready

    #pragma unroll
    for (int mi = 0; mi < 6; ++mi)
        wnx[mi] = *(const bfrag8*)(wl + (0 * 6 + mi) * 1024 + lane * 16);

    #pragma unroll
    for (int kc = 0; kc < 4; ++kc) {
        bfrag8 wcur[6];
        #pragma unroll
        for (int mi = 0; mi < 6; ++mi) wcur[mi] = wnx[mi];
        if (kc < 3) {
            #pragma unroll
            for (int mi = 0; mi < 6; ++mi)
                wnx[mi] = *(const bfrag8*)(wl + ((kc + 1) * 6 + mi) * 1024 + lane * 16);
        }
        #pragma unroll
        for (int mi = 0; mi < 6; ++mi)
            #pragma unroll
            for (int ci = 0; ci < 2; ++ci)
                acc[mi][ci] = __builtin_amdgcn_mfma_f32_16x16x32_bf16(wcur[mi], bnx[4 + kc][ci], acc[mi][ci], 0, 0, 0);
    }
    __syncthreads();   // all waves done reading chunk B — overlay now safe

    const float* biasl = (const float*)(lds + LDS_BIAS_OFF);
    char* kmv = lds;                 // km rows 0..31, v rows 32..63, stride 272
    char* qs  = lds + LDS_QS_OFF;    // qm [n 128][80 B]
    #pragma unroll
    for (int mi = 0; mi < 2; ++mi)
        #pragma unroll
        for (int ci = 0; ci < 2; ++ci)
            #pragma unroll
            for (int r = 0; r < 4; ++r) {
                int d = mi * 16 + lq * 4 + r;
                int n = w * 32 + ci * 16 + lr;
                float q = acc[mi][ci][r] + biasl[d];
                *(unsigned short*)(qs + n * 80 + d * 2) = f2b(q > 0.f ? q + 1.f : __expf(q));
            }
    #pragma unroll
    for (int mi = 2; mi < 4; ++mi)
        #pragma unroll
        for (int ci = 0; ci < 2; ++ci)
            #pragma unroll
            for (int r = 0; r < 4; ++r) {
                int d = (mi - 2) * 16 + lq * 4 + r;
                int n = w * 32 + ci * 16 + lr;
                float kk = acc[mi][ci][r] + biasl[32 + d];
                *(unsigned short*)(kmv + d * 272 + n * 2) = f2b(kk > 0.f ? kk + 1.f : __expf(kk));
            }
    #pragma unroll
    for (int mi = 4; mi < 6; ++mi)
        #pragma unroll
        for (int ci = 0; ci < 2; ++ci)
            #pragma unroll
            for (int r = 0; r < 4; ++r) {
                int e = (mi - 4) * 16 + lq * 4 + r;
                int n = w * 32 + ci * 16 + lr;
                *(unsigned short*)(kmv + (32 + e) * 272 + n * 2) = f2b(acc[mi][ci][r] + biasl[64 + e]);
            }
    __syncthreads();

    float* ctx2p = ctx2 + (size_t)(b * NHEAD + h) * 1056;

    {
        char* qg = (char*)(qm_t + ((size_t)(b * NHEAD + h) * NNTOK + n0) * 32);
        int n = t >> 1, half = t & 1;
        const char* src = qs + n * 80 + half * 32;
        char* dst = qg + n * 64 + half * 32;
        *(float4*)dst = *(const float4*)src;
        *(float4*)(dst + 16) = *(const float4*)(src + 16);
    }

    {
        int qr = w >> 1, qc = w & 1;
        accf4 cacc = (accf4){0.f, 0.f, 0.f, 0.f};
        #pragma unroll
        for (int kk = 0; kk < 4; ++kk) {
            bfrag8 a  = *(const bfrag8*)(kmv + (qr * 16 + lr) * 272 + kk * 64 + lq * 16);
            bfrag8 bb = *(const bfrag8*)(kmv + (32 + qc * 16 + lr) * 272 + kk * 64 + lq * 16);
            cacc = __builtin_amdgcn_mfma_f32_16x16x32_bf16(a, bb, cacc, 0, 0, 0);
        }
        #pragma unroll
        for (int r = 0; r < 4; ++r) {
            int d = qr * 16 + lq * 4 + r, e = qc * 16 + lr;
            atomicAdd(ctx2p + d * 32 + e, cacc[r]);
        }
    }

    {
        float* ksp = (float*)(lds + LDS_KSP_OFF);
        int d = t >> 3, oc = t & 7;
        float s = 0.f;
        for (int i = 0; i < 16; ++i)
            s += b2f(*(const unsigned short*)(kmv + d * 272 + (oc * 16 + i) * 2));
        ksp[d * 8 + oc] = s;
        __syncthreads();
        if (t < 32) {
            float s2 = 0.f;
            #pragma unroll
            for (int i = 0; i < 8; ++i) s2 += ksp[t * 8 + i];
            atomicAdd(ctx2p + 1024 + t, s2);
        }
    }
}

// ============ Kernel 5: build A (bf16) + finalize ksum (R10 verbatim) ============
__global__ __launch_bounds__(256) void build_A(const float* __restrict__ w_out,
                                               const float* __restrict__ ctx2,
                                               unsigned short* __restrict__ Amat,
                                               float* __restrict__ ksum_g) {
    int ot = blockIdx.x, b = blockIdx.y, t = threadIdx.x;
    __shared__ float cs[NHEAD * HD * HD];
    for (int i = t; i < NHEAD * HD * HD; i += 256) {
        int hh = i >> 10, de = i & 1023;
        cs[i] = ctx2[(size_t)(b * NHEAD + hh) * 1056 + de];
    }
    if (ot == 0)
        ksum_g[b * CC + t] = ctx2[(size_t)(b * NHEAD + (t >> 5)) * 1056 + 1024 + (t & 31)];
    __syncthreads();
    int h = t >> 5, d = t & 31;
    for (int oi = 0; oi < 32; ++oi) {
        int o = ot * 32 + oi;
        const float* wrow = w_out + (size_t)o * CC + h * HD;
        float s = 0.f;
        #pragma unroll
        for (int e = 0; e < HD; ++e) s += wrow[e] * cs[h * 1024 + d * 32 + e];
        Amat[((size_t)(b * CC + o)) * CC + t] = f2b(s);
    }
}

// ============ Kernel 6: out = A @ (qm*den) + b_out + x (R6-verified, R10 verbatim) ============
#define LDSF_A   0
#define LDSF_Q   10240
#define LDSF_BO  20480      // 128 f32
#define LDSF_KS  20992      // 256 f32
#define LDSF_TOT 22016
__global__ __launch_bounds__(256, 4) void final_out(
    const unsigned short* __restrict__ qm_t, const unsigned short* __restrict__ Amat,
    const float* __restrict__ ksum_g, const float* __restrict__ b_out,
    const float* __restrict__ x, float* __restrict__ out) {
    __shared__ char L[LDSF_TOT];
    int tile = blockIdx.x, mt = blockIdx.y, b = blockIdx.z;
    int n0 = tile * 128, t = threadIdx.x;
    int lane = t & 63, w = t >> 6, lr = lane & 15, lq = lane >> 4;
    int wm = (w >> 1) * 64, wn = (w & 1) * 64;
    accf4 acc[4][4];
    #pragma unroll
    for (int i = 0; i < 4; ++i)
        #pragma unroll
        for (int j = 0; j < 4; ++j) acc[i][j] = (accf4){0.f, 0.f, 0.f, 0.f};

    if (t < 128) ((float*)(L + LDSF_BO))[t] = b_out[mt * 128 + t];
    ((float*)(L + LDSF_KS))[t] = ksum_g[b * CC + t];

    char* Al = L + LDSF_A;
    char* Ql = L + LDSF_Q;
    const int m = t >> 1, half = t & 1;
    const char* ag = (const char*)(Amat + (size_t)(b * CC + mt * 128 + m) * CC) + half * 32;
    const char* qg = (const char*)(qm_t + ((size_t)b * NHEAD * NNTOK + (size_t)(n0 + m)) * 32) + half * 32;

    bfrag8 a0 = *(const bfrag8*)ag;
    bfrag8 a1 = *(const bfrag8*)(ag + 16);
    bfrag8 q0 = *(const bfrag8*)qg;
    bfrag8 q1 = *(const bfrag8*)(qg + 16);

    __syncthreads();   // ksum/bo visible

    for (int h = 0; h < NHEAD; ++h) {
        const float* ks = (const float*)(L + LDSF_KS) + h * 32 + half * 16;
        float sp = 0.f;
        #pragma unroll
        for (int e = 0; e < 8; ++e) {
            sp += b2f((unsigned short)q0[e]) * ks[e];
            sp += b2f((unsigned short)q1[e]) * ks[8 + e];
        }
        float dot = sp + __shfl_xor(sp, 1);
        float dn = 1.0f / (dot + ATT_EPS);

        __syncthreads();   // previous head's MFMA done reading LDS
        *(bfrag8*)(Al + m * 80 + half * 32) = a0;
        *(bfrag8*)(Al + m * 80 + half * 32 + 16) = a1;
        bfrag8 s0, s1;
        #pragma unroll
        for (int e = 0; e < 8; ++e) {
            s0[e] = (short)f2b(b2f((unsigned short)q0[e]) * dn);
            s1[e] = (short)f2b(b2f((unsigned short)q1[e]) * dn);
        }
        *(bfrag8*)(Ql + m * 80 + half * 32) = s0;
        *(bfrag8*)(Ql + m * 80 + half * 32 + 16) = s1;
        __syncthreads();   // tiles ready

        if (h < 7) {       // prefetch next head during MFMA
            a0 = *(const bfrag8*)(ag + (h + 1) * 64);
            a1 = *(const bfrag8*)(ag + (h + 1) * 64 + 16);
            q0 = *(const bfrag8*)(qg + (size_t)(h + 1) * NNTOK * 64);
            q1 = *(const bfrag8*)(qg + (size_t)(h + 1) * NNTOK * 64 + 16);
        }

        bfrag8 bfr[4];
        #pragma unroll
        for (int ci = 0; ci < 4; ++ci) {
            int n = wn + ci * 16 + lr;
            bfr[ci] = *(const bfrag8*)(Ql + n * 80 + lq * 16);
        }
        #pragma unroll
        for (int mi = 0; mi < 4; ++mi) {
            bfrag8 a = *(const bfrag8*)(Al + (wm + mi * 16 + lr) * 80 + lq * 16);
            #pragma unroll
            for (int ci = 0; ci < 4; ++ci)
                acc[mi][ci] = __builtin_amdgcn_mfma_f32_16x16x32_bf16(a, bfr[ci], acc[mi][ci], 0, 0, 0);
        }
    }

    const float* bo_s = (const float*)(L + LDSF_BO);
    #pragma unroll
    for (int mi = 0; mi < 4; ++mi)
        #pragma unroll
        for (int ci = 0; ci < 4; ++ci)
            #pragma unroll
            for (int r = 0; r < 4; ++r) {
                int ol = wm + mi * 16 + lq * 4 + r;
                int n = wn + ci * 16 + lr;
                size_t idx = ((size_t)(b * CC + mt * 128 + ol)) * NNTOK + n0 + n;
                out[idx] = acc[mi][ci][r] + bo_s[ol] + x[idx];
            }
}

extern "C" void kernel_launch(void* const* d_in, const int* in_sizes, int n_in,
                              void* d_out, int out_size, void* d_ws, size_t ws_size,
                              hipStream_t stream) {
    (void)in_sizes; (void)n_in; (void)out_size; (void)ws_size;
    const float* x      = (const float*)d_in[0];
    const float* gamma  = (const float*)d_in[1];
    const float* beta   = (const float*)d_in[2];
    const float* wq     = (const float*)d_in[3];
    const float* wk     = (const float*)d_in[4];
    const float* wv     = (const float*)d_in[5];
    const float* w_out  = (const float*)d_in[6];
    const float* b_out  = (const float*)d_in[7];
    float* out = (float*)d_out;
    float* ws  = (float*)d_ws;

    unsigned short* qm_t = (unsigned short*)(ws + WS_QMT);
    unsigned short* xn_t = (unsigned short*)(ws + WS_XNT);
    float* ctx2 = ws + WS_CTX2;
    float* gnp2 = ws + WS_GNP2;
    unsigned short* Wst2 = (unsigned short*)(ws + WS_WST2);
    float* bias = ws + WS_BIAS;
    float* scale = ws + WS_SCALE;
    float* shift = ws + WS_SHIFT;
    float* ksum = ws + WS_KSUM;
    unsigned short* Amat = (unsigned short*)(ws + WS_AMAT);

    hipLaunchKernelGGL(xn_gn, dim3(NNTOK / 64, BB), dim3(256), 0, stream, x, xn_t, gnp2);
    hipLaunchKernelGGL(gn_stats2, dim3(1), dim3(256), 0, stream, gnp2, gamma, beta,
                       scale, shift);
    hipLaunchKernelGGL(fold_w, dim3(8, 8, 2), dim3(256), 0, stream, wq, wk, wv,
                       scale, shift, Wst2, bias, ctx2);
    hipLaunchKernelGGL(qkv_ctx, dim3(NNTOK / 128 * NHEAD * BB), dim3(256), 0, stream,
                       xn_t, Wst2, bias, qm_t, ctx2);
    hipLaunchKernelGGL(build_A, dim3(8, BB), dim3(256), 0, stream, w_out, ctx2, Amat, ksum);
    hipLaunchKernelGGL(final_out, dim3(NNTOK / 128, 2, BB), dim3(256), 0, stream,
                       qm_t, Amat, ksum, b_out, x, out);
}

// Round 12
// 256.396 us; speedup vs baseline: 1.1164x; 1.1164x over previous
//
#include <hip/hip_runtime.h>
#include <math.h>

#define BB 2
#define CC 256
#define NHEAD 8
#define HD 32
#define NGRP 8
#define NNTOK 32768
#define ATT_EPS 1e-6f
#define GN_EPS 1e-5f

typedef __attribute__((ext_vector_type(8))) short bfrag8;   // 8 bf16
typedef __attribute__((ext_vector_type(4))) float accf4;    // MFMA C/D 16x16

__device__ __forceinline__ float b2f(unsigned short u) {
    unsigned int x = ((unsigned int)u) << 16;
    return __uint_as_float(x);
}
__device__ __forceinline__ unsigned short f2b(float f) {
    unsigned int x = __float_as_uint(f);
    unsigned int r = x + 0x7fffu + ((x >> 16) & 1u);
    return (unsigned short)(r >> 16);
}
__device__ __forceinline__ void gl_lds16(const void* g, void* s) {
    __builtin_amdgcn_global_load_lds(
        (const __attribute__((address_space(1))) unsigned int*)g,
        (__attribute__((address_space(3))) unsigned int*)s, 16, 0, 0);
}

// ---- workspace layout (float offsets) ----
#define WS_QMT   0ull                      // bf16 [B][H][N][32]
#define WS_XNT   (WS_QMT + 8388608ull)     // bf16 [B][N][264] raw-x transpose
#define WS_WSTOLD (WS_XNT + 8650752ull)    // (old region, unused)
#define WS_PART  (WS_WSTOLD + 101632ull)   // big scratch region
#define WS_CTX2  WS_PART                   // f32 [16 bh][1056] atomic accumulators
#define WS_GNP2  (WS_PART + 135168ull)     // f32 [1024 blk][16] GN partials
#define WS_WST2  (WS_PART + 151552ull)     // bf16 [B*H][24576] folded W (frag-linear)
#define WS_BIAS  (WS_PART + 348160ull)     // f32 [B*H][96]
#define WS_GNPO  (WS_PART + 4325376ull)    // old chain (layout stability)
#define WS_SCALE (WS_GNPO + 2048ull)       // f32 [B][256]
#define WS_SHIFT (WS_SCALE + 512ull)       // f32 [B][256]
#define WS_CTXO  (WS_SHIFT + 512ull)
#define WS_KSUM  (WS_CTXO + 16384ull)      // f32 [B][H][32]
#define WS_AMAT  (WS_KSUM + 512ull)        // bf16 [B][256][256]

// LDS for qkv_ctx (29184 B): mainloop W chunk 24KB @0 (kc-half staged twice);
// epilogue overlay: kmv 64x272 @0, qs 128x80 @17408, ksp @27648; bias @28672
// (outside W chunk, persists). 4 blocks/CU at launch_bounds(256,4):
// VGPR cap 128 >= ~84 used (R11's (256,5) capped at ~96 -> SPILLED, 242MB scratch).
#define LDS_QS_OFF  17408
#define LDS_KSP_OFF 27648
#define LDS_BIAS_OFF 28672
#define LDS_QKV_TOTAL 29184

// ============ Kernel 1: fused x transpose->bf16 + GN partial sums (R10 verbatim) ============
__global__ __launch_bounds__(256) void xn_gn(const float* __restrict__ x,
                                             unsigned short* __restrict__ xn_t,
                                             float* __restrict__ gnp2) {
    __shared__ unsigned short xt[64][264];   // row = token, 528 B/row
    int b = blockIdx.y, n0 = blockIdx.x * 64, t = threadIdx.x;
    int g16 = t >> 4, ip = t & 15, col4 = ip * 4;
    float gs = 0.f, gs2 = 0.f;
    bfrag8 pk0, pk1, pk2, pk3;
    #pragma unroll
    for (int i = 0; i < 16; ++i) {
        int c = g16 * 16 + i;
        const float4 v = *(const float4*)(x + (size_t)(b * CC + c) * NNTOK + n0 + col4);
        gs  += v.x + v.y + v.z + v.w;
        gs2 += v.x * v.x + v.y * v.y + v.z * v.z + v.w * v.w;
        int k = i & 7;
        pk0[k] = (short)f2b(v.x);
        pk1[k] = (short)f2b(v.y);
        pk2[k] = (short)f2b(v.z);
        pk3[k] = (short)f2b(v.w);
        if (k == 7) {
            int cb = g16 * 32 + (i >> 3) * 16;   // byte offset of channel batch
            char* base = (char*)&xt[0][0] + cb;
            *(bfrag8*)(base + (col4 + 0) * 528) = pk0;
            *(bfrag8*)(base + (col4 + 1) * 528) = pk1;
            *(bfrag8*)(base + (col4 + 2) * 528) = pk2;
            *(bfrag8*)(base + (col4 + 3) * 528) = pk3;
        }
    }
    int lane = t & 63, w = t >> 6;
    #pragma unroll
    for (int off = 16; off; off >>= 1) {
        gs  += __shfl_down(gs, off);
        gs2 += __shfl_down(gs2, off);
    }
    if (lane == 0 || lane == 32) {
        int g = 2 * w + (lane >> 5);
        float* gp = gnp2 + (size_t)(b * 512 + blockIdx.x) * 16;
        gp[g * 2] = gs;
        gp[g * 2 + 1] = gs2;
    }
    __syncthreads();
    int n = t >> 2, q = t & 3;
    const char* src = (const char*)&xt[n][0] + q * 128;
    char* dst = (char*)(xn_t + ((size_t)b * NNTOK + n0 + n) * 264) + q * 128;
    #pragma unroll
    for (int i = 0; i < 8; ++i)
        *(float4*)(dst + i * 16) = *(const float4*)(src + i * 16);
}

// ============ Kernel 2: finalize GN stats -> scale/shift (R10 verbatim) ============
__global__ __launch_bounds__(256) void gn_stats2(const float* __restrict__ gnp2,
                                                 const float* __restrict__ gamma,
                                                 const float* __restrict__ beta,
                                                 float* __restrict__ scale,
                                                 float* __restrict__ shift) {
    __shared__ float red[256];
    __shared__ float mean_l[16], rstd_l[16];
    int t = threadIdx.x;
    int combo = t >> 3, sl = t & 7;      // combo = b2*16 + idx (idx = g*2+sel)
    int b2 = combo >> 4, idx = combo & 15;
    float a = 0.f;
    for (int k = sl; k < 512; k += 8)
        a += gnp2[(size_t)(b2 * 512 + k) * 16 + idx];
    red[t] = a;
    __syncthreads();
    if (t < 32) {
        float s = 0.f;
        #pragma unroll
        for (int j = 0; j < 8; ++j) s += red[t * 8 + j];
        red[t] = s;                      // stats[combo]
    }
    __syncthreads();
    if (t < 16) {
        const float inv = 1.0f / (float)((CC / NGRP) * NNTOK);
        float m = red[t * 2] * inv;
        float var = red[t * 2 + 1] * inv - m * m;
        mean_l[t] = m;
        rstd_l[t] = rsqrtf(var + GN_EPS);
    }
    __syncthreads();
    for (int i = t; i < BB * CC; i += 256) {
        int b = i >> 8, c = i & 255;
        int g = b * 8 + (c >> 5);
        float sc = gamma[c] * rstd_l[g];
        scale[i] = sc;
        shift[i] = beta[c] - mean_l[g] * sc;
    }
}

// ============ Kernel 3: fold scale into W + bias + distributed ctx2 zero (R10 verbatim) ============
__global__ __launch_bounds__(256) void fold_w(const float* __restrict__ wq,
                                              const float* __restrict__ wk,
                                              const float* __restrict__ wv,
                                              const float* __restrict__ scale,
                                              const float* __restrict__ shift,
                                              unsigned short* __restrict__ Wst2,
                                              float* __restrict__ bias,
                                              float* __restrict__ ctx2) {
    int slice = blockIdx.x, h = blockIdx.y, b2 = blockIdx.z, t = threadIdx.x;
    {
        int lin = slice + h * 8 + b2 * 64;   // 0..127
        int i = lin * 132 + t;
        if (t < 132) ctx2[i] = 0.f;
    }
    __shared__ float sc_l[256], sh_l[256];
    sc_l[t] = scale[b2 * CC + t];
    sh_l[t] = shift[b2 * CC + t];
    __syncthreads();
    const float* Ws[3] = {wq, wk, wv};
    unsigned short* wdst = Wst2 + (size_t)(b2 * NHEAD + h) * 24576;
    for (int i = slice * 3072 + t; i < (slice + 1) * 3072; i += 256) {
        int e = i & 7;
        int chunk = i >> 3;
        int lane = chunk & 63;
        int kcmi = chunk >> 6;
        int mi = kcmi % 6;
        int kc = kcmi / 6;
        int lr = lane & 15, lq = lane >> 4;
        int row = mi * 16 + lr;
        int col = kc * 32 + lq * 8 + e;
        float v = Ws[row >> 5][(size_t)(h * 32 + (row & 31)) * CC + col] * sc_l[col];
        wdst[i] = f2b(v);
    }
    if (t < 96) {
        int rl = t >> 3, sub = t & 7;
        int r = slice * 12 + rl;
        const float* wrow = Ws[r >> 5] + (size_t)(h * 32 + (r & 31)) * CC + sub * 32;
        float sp = 0.f;
        #pragma unroll
        for (int k = 0; k < 8; ++k) {
            const float4 v4 = *(const float4*)(wrow + k * 4);
            const float* shp = &sh_l[sub * 32 + k * 4];
            sp += v4.x * shp[0] + v4.y * shp[1] + v4.z * shp[2] + v4.w * shp[3];
        }
        sp += __shfl_xor(sp, 1);
        sp += __shfl_xor(sp, 2);
        sp += __shfl_xor(sp, 4);
        if (sub == 0) bias[(size_t)(b2 * NHEAD + h) * 96 + r] = sp;
    }
}

// ============ Kernel 4: fused QKV MFMA + bias + elu + ctx/ksum atomics ============
// R11 two-chunk staging; launch_bounds (256,4): VGPR cap 128 (no spill),
// LDS 29.2KB -> 4 blocks/CU = 16 waves (R10: 12 waves at 49.7KB).
__global__ __launch_bounds__(256, 4) void qkv_ctx(
    const unsigned short* __restrict__ xn_t, const unsigned short* __restrict__ Wst2,
    const float* __restrict__ bias,
    unsigned short* __restrict__ qm_t, float* __restrict__ ctx2) {
    __shared__ char lds[LDS_QKV_TOTAL];
    const int id = blockIdx.x;
    const int xcd = id & 7;
    const int j = id >> 3;
    const int h = j & 7;
    const int rem = j >> 3;                 // 0..63
    const int tile = xcd * 32 + (rem & 31);
    const int b = rem >> 5;
    const int t = threadIdx.x;
    const int lane = t & 63, w = t >> 6;
    const int lr = lane & 15, lq = lane >> 4;
    const int n0 = tile * 128;

    const char* wg = (const char*)(Wst2 + (size_t)(b * NHEAD + h) * 24576);

    // stage W chunk A (kc 0..3, 24KB) + bias
    for (int jj = w; jj < 24; jj += 4)
        gl_lds16(wg + jj * 1024 + lane * 16, lds + jj * 1024);
    if (t < 96)
        ((float*)(lds + LDS_BIAS_OFF))[t] = bias[(size_t)(b * NHEAD + h) * 96 + t];

    // issue ALL xn fragment loads now — they complete during the stage drain
    const unsigned short* xr0 = xn_t + ((size_t)b * NNTOK + n0 + w * 32 + lr) * 264 + lq * 8;
    const unsigned short* xr1 = xr0 + 16 * 264;
    bfrag8 bnx[8][2];
    #pragma unroll
    for (int kc = 0; kc < 8; ++kc) {
        bnx[kc][0] = *(const bfrag8*)(xr0 + kc * 32);
        bnx[kc][1] = *(const bfrag8*)(xr1 + kc * 32);
    }
    __syncthreads();   // chunk A ready (drains all vmem)

    accf4 acc[6][2];
    #pragma unroll
    for (int i = 0; i < 6; ++i)
        #pragma unroll
        for (int jj = 0; jj < 2; ++jj) acc[i][jj] = (accf4){0.f, 0.f, 0.f, 0.f};

    const char* wl = lds;
    bfrag8 wnx[6];
    #pragma unroll
    for (int mi = 0; mi < 6; ++mi)
        wnx[mi] = *(const bfrag8*)(wl + (0 * 6 + mi) * 1024 + lane * 16);

    #pragma unroll
    for (int kc = 0; kc < 4; ++kc) {
        bfrag8 wcur[6];
        #pragma unroll
        for (int mi = 0; mi < 6; ++mi) wcur[mi] = wnx[mi];
        if (kc < 3) {
            #pragma unroll
            for (int mi = 0; mi < 6; ++mi)
                wnx[mi] = *(const bfrag8*)(wl + ((kc + 1) * 6 + mi) * 1024 + lane * 16);
        }
        #pragma unroll
        for (int mi = 0; mi < 6; ++mi)
            #pragma unroll
            for (int ci = 0; ci < 2; ++ci)
                acc[mi][ci] = __builtin_amdgcn_mfma_f32_16x16x32_bf16(wcur[mi], bnx[kc][ci], acc[mi][ci], 0, 0, 0);
    }
    __syncthreads();   // all waves done reading chunk A

    // stage W chunk B (kc 4..7) into the same buffer
    for (int jj = w; jj < 24; jj += 4)
        gl_lds16(wg + (24 + jj) * 1024 + lane * 16, lds + jj * 1024);
    __syncthreads();   // chunk B ready

    #pragma unroll
    for (int mi = 0; mi < 6; ++mi)
        wnx[mi] = *(const bfrag8*)(wl + (0 * 6 + mi) * 1024 + lane * 16);

    #pragma unroll
    for (int kc = 0; kc < 4; ++kc) {
        bfrag8 wcur[6];
        #pragma unroll
        for (int mi = 0; mi < 6; ++mi) wcur[mi] = wnx[mi];
        if (kc < 3) {
            #pragma unroll
            for (int mi = 0; mi < 6; ++mi)
                wnx[mi] = *(const bfrag8*)(wl + ((kc + 1) * 6 + mi) * 1024 + lane * 16);
        }
        #pragma unroll
        for (int mi = 0; mi < 6; ++mi)
            #pragma unroll
            for (int ci = 0; ci < 2; ++ci)
                acc[mi][ci] = __builtin_amdgcn_mfma_f32_16x16x32_bf16(wcur[mi], bnx[4 + kc][ci], acc[mi][ci], 0, 0, 0);
    }
    __syncthreads();   // all waves done reading chunk B — overlay now safe

    const float* biasl = (const float*)(lds + LDS_BIAS_OFF);
    char* kmv = lds;                 // km rows 0..31, v rows 32..63, stride 272
    char* qs  = lds + LDS_QS_OFF;    // qm [n 128][80 B]
    #pragma unroll
    for (int mi = 0; mi < 2; ++mi)
        #pragma unroll
        for (int ci = 0; ci < 2; ++ci)
            #pragma unroll
            for (int r = 0; r < 4; ++r) {
                int d = mi * 16 + lq * 4 + r;
                int n = w * 32 + ci * 16 + lr;
                float q = acc[mi][ci][r] + biasl[d];
                *(unsigned short*)(qs + n * 80 + d * 2) = f2b(q > 0.f ? q + 1.f : __expf(q));
            }
    #pragma unroll
    for (int mi = 2; mi < 4; ++mi)
        #pragma unroll
        for (int ci = 0; ci < 2; ++ci)
            #pragma unroll
            for (int r = 0; r < 4; ++r) {
                int d = (mi - 2) * 16 + lq * 4 + r;
                int n = w * 32 + ci * 16 + lr;
                float kk = acc[mi][ci][r] + biasl[32 + d];
                *(unsigned short*)(kmv + d * 272 + n * 2) = f2b(kk > 0.f ? kk + 1.f : __expf(kk));
            }
    #pragma unroll
    for (int mi = 4; mi < 6; ++mi)
        #pragma unroll
        for (int ci = 0; ci < 2; ++ci)
            #pragma unroll
            for (int r = 0; r < 4; ++r) {
                int e = (mi - 4) * 16 + lq * 4 + r;
                int n = w * 32 + ci * 16 + lr;
                *(unsigned short*)(kmv + (32 + e) * 272 + n * 2) = f2b(acc[mi][ci][r] + biasl[64 + e]);
            }
    __syncthreads();

    float* ctx2p = ctx2 + (size_t)(b * NHEAD + h) * 1056;

    {
        char* qg = (char*)(qm_t + ((size_t)(b * NHEAD + h) * NNTOK + n0) * 32);
        int n = t >> 1, half = t & 1;
        const char* src = qs + n * 80 + half * 32;
        char* dst = qg + n * 64 + half * 32;
        *(float4*)dst = *(const float4*)src;
        *(float4*)(dst + 16) = *(const float4*)(src + 16);
    }

    {
        int qr = w >> 1, qc = w & 1;
        accf4 cacc = (accf4){0.f, 0.f, 0.f, 0.f};
        #pragma unroll
        for (int kk = 0; kk < 4; ++kk) {
            bfrag8 a  = *(const bfrag8*)(kmv + (qr * 16 + lr) * 272 + kk * 64 + lq * 16);
            bfrag8 bb = *(const bfrag8*)(kmv + (32 + qc * 16 + lr) * 272 + kk * 64 + lq * 16);
            cacc = __builtin_amdgcn_mfma_f32_16x16x32_bf16(a, bb, cacc, 0, 0, 0);
        }
        #pragma unroll
        for (int r = 0; r < 4; ++r) {
            int d = qr * 16 + lq * 4 + r, e = qc * 16 + lr;
            atomicAdd(ctx2p + d * 32 + e, cacc[r]);
        }
    }

    {
        float* ksp = (float*)(lds + LDS_KSP_OFF);
        int d = t >> 3, oc = t & 7;
        float s = 0.f;
        for (int i = 0; i < 16; ++i)
            s += b2f(*(const unsigned short*)(kmv + d * 272 + (oc * 16 + i) * 2));
        ksp[d * 8 + oc] = s;
        __syncthreads();
        if (t < 32) {
            float s2 = 0.f;
            #pragma unroll
            for (int i = 0; i < 8; ++i) s2 += ksp[t * 8 + i];
            atomicAdd(ctx2p + 1024 + t, s2);
        }
    }
}

// ============ Kernel 5: build A (bf16) + finalize ksum (R10 verbatim) ============
__global__ __launch_bounds__(256) void build_A(const float* __restrict__ w_out,
                                               const float* __restrict__ ctx2,
                                               unsigned short* __restrict__ Amat,
                                               float* __restrict__ ksum_g) {
    int ot = blockIdx.x, b = blockIdx.y, t = threadIdx.x;
    __shared__ float cs[NHEAD * HD * HD];
    for (int i = t; i < NHEAD * HD * HD; i += 256) {
        int hh = i >> 10, de = i & 1023;
        cs[i] = ctx2[(size_t)(b * NHEAD + hh) * 1056 + de];
    }
    if (ot == 0)
        ksum_g[b * CC + t] = ctx2[(size_t)(b * NHEAD + (t >> 5)) * 1056 + 1024 + (t & 31)];
    __syncthreads();
    int h = t >> 5, d = t & 31;
    for (int oi = 0; oi < 32; ++oi) {
        int o = ot * 32 + oi;
        const float* wrow = w_out + (size_t)o * CC + h * HD;
        float s = 0.f;
        #pragma unroll
        for (int e = 0; e < HD; ++e) s += wrow[e] * cs[h * 1024 + d * 32 + e];
        Amat[((size_t)(b * CC + o)) * CC + t] = f2b(s);
    }
}

// ============ Kernel 6: out = A @ (qm*den) + b_out + x (R6-verified, R10 verbatim) ============
#define LDSF_A   0
#define LDSF_Q   10240
#define LDSF_BO  20480      // 128 f32
#define LDSF_KS  20992      // 256 f32
#define LDSF_TOT 22016
__global__ __launch_bounds__(256, 4) void final_out(
    const unsigned short* __restrict__ qm_t, const unsigned short* __restrict__ Amat,
    const float* __restrict__ ksum_g, const float* __restrict__ b_out,
    const float* __restrict__ x, float* __restrict__ out) {
    __shared__ char L[LDSF_TOT];
    int tile = blockIdx.x, mt = blockIdx.y, b = blockIdx.z;
    int n0 = tile * 128, t = threadIdx.x;
    int lane = t & 63, w = t >> 6, lr = lane & 15, lq = lane >> 4;
    int wm = (w >> 1) * 64, wn = (w & 1) * 64;
    accf4 acc[4][4];
    #pragma unroll
    for (int i = 0; i < 4; ++i)
        #pragma unroll
        for (int j = 0; j < 4; ++j) acc[i][j] = (accf4){0.f, 0.f, 0.f, 0.f};

    if (t < 128) ((float*)(L + LDSF_BO))[t] = b_out[mt * 128 + t];
    ((float*)(L + LDSF_KS))[t] = ksum_g[b * CC + t];

    char* Al = L + LDSF_A;
    char* Ql = L + LDSF_Q;
    const int m = t >> 1, half = t & 1;
    const char* ag = (const char*)(Amat + (size_t)(b * CC + mt * 128 + m) * CC) + half * 32;
    const char* qg = (const char*)(qm_t + ((size_t)b * NHEAD * NNTOK + (size_t)(n0 + m)) * 32) + half * 32;

    bfrag8 a0 = *(const bfrag8*)ag;
    bfrag8 a1 = *(const bfrag8*)(ag + 16);
    bfrag8 q0 = *(const bfrag8*)qg;
    bfrag8 q1 = *(const bfrag8*)(qg + 16);

    __syncthreads();   // ksum/bo visible

    for (int h = 0; h < NHEAD; ++h) {
        const float* ks = (const float*)(L + LDSF_KS) + h * 32 + half * 16;
        float sp = 0.f;
        #pragma unroll
        for (int e = 0; e < 8; ++e) {
            sp += b2f((unsigned short)q0[e]) * ks[e];
            sp += b2f((unsigned short)q1[e]) * ks[8 + e];
        }
        float dot = sp + __shfl_xor(sp, 1);
        float dn = 1.0f / (dot + ATT_EPS);

        __syncthreads();   // previous head's MFMA done reading LDS
        *(bfrag8*)(Al + m * 80 + half * 32) = a0;
        *(bfrag8*)(Al + m * 80 + half * 32 + 16) = a1;
        bfrag8 s0, s1;
        #pragma unroll
        for (int e = 0; e < 8; ++e) {
            s0[e] = (short)f2b(b2f((unsigned short)q0[e]) * dn);
            s1[e] = (short)f2b(b2f((unsigned short)q1[e]) * dn);
        }
        *(bfrag8*)(Ql + m * 80 + half * 32) = s0;
        *(bfrag8*)(Ql + m * 80 + half * 32 + 16) = s1;
        __syncthreads();   // tiles ready

        if (h < 7) {       // prefetch next head during MFMA
            a0 = *(const bfrag8*)(ag + (h + 1) * 64);
            a1 = *(const bfrag8*)(ag + (h + 1) * 64 + 16);
            q0 = *(const bfrag8*)(qg + (size_t)(h + 1) * NNTOK * 64);
            q1 = *(const bfrag8*)(qg + (size_t)(h + 1) * NNTOK * 64 + 16);
        }

        bfrag8 bfr[4];
        #pragma unroll
        for (int ci = 0; ci < 4; ++ci) {
            int n = wn + ci * 16 + lr;
            bfr[ci] = *(const bfrag8*)(Ql + n * 80 + lq * 16);
        }
        #pragma unroll
        for (int mi = 0; mi < 4; ++mi) {
            bfrag8 a = *(const bfrag8*)(Al + (wm + mi * 16 + lr) * 80 + lq * 16);
            #pragma unroll
            for (int ci = 0; ci < 4; ++ci)
                acc[mi][ci] = __builtin_amdgcn_mfma_f32_16x16x32_bf16(a, bfr[ci], acc[mi][ci], 0, 0, 0);
        }
    }

    const float* bo_s = (const float*)(L + LDSF_BO);
    #pragma unroll
    for (int mi = 0; mi < 4; ++mi)
        #pragma unroll
        for (int ci = 0; ci < 4; ++ci)
            #pragma unroll
            for (int r = 0; r < 4; ++r) {
                int ol = wm + mi * 16 + lq * 4 + r;
                int n = wn + ci * 16 + lr;
                size_t idx = ((size_t)(b * CC + mt * 128 + ol)) * NNTOK + n0 + n;
                out[idx] = acc[mi][ci][r] + bo_s[ol] + x[idx];
            }
}

extern "C" void kernel_launch(void* const* d_in, const int* in_sizes, int n_in,
                              void* d_out, int out_size, void* d_ws, size_t ws_size,
                              hipStream_t stream) {
    (void)in_sizes; (void)n_in; (void)out_size; (void)ws_size;
    const float* x      = (const float*)d_in[0];
    const float* gamma  = (const float*)d_in[1];
    const float* beta   = (const float*)d_in[2];
    const float* wq     = (const float*)d_in[3];
    const float* wk     = (const float*)d_in[4];
    const float* wv     = (const float*)d_in[5];
    const float* w_out  = (const float*)d_in[6];
    const float* b_out  = (const float*)d_in[7];
    float* out = (float*)d_out;
    float* ws  = (float*)d_ws;

    unsigned short* qm_t = (unsigned short*)(ws + WS_QMT);
    unsigned short* xn_t = (unsigned short*)(ws + WS_XNT);
    float* ctx2 = ws + WS_CTX2;
    float* gnp2 = ws + WS_GNP2;
    unsigned short* Wst2 = (unsigned short*)(ws + WS_WST2);
    float* bias = ws + WS_BIAS;
    float* scale = ws + WS_SCALE;
    float* shift = ws + WS_SHIFT;
    float* ksum = ws + WS_KSUM;
    unsigned short* Amat = (unsigned short*)(ws + WS_AMAT);

    hipLaunchKernelGGL(xn_gn, dim3(NNTOK / 64, BB), dim3(256), 0, stream, x, xn_t, gnp2);
    hipLaunchKernelGGL(gn_stats2, dim3(1), dim3(256), 0, stream, gnp2, gamma, beta,
                       scale, shift);
    hipLaunchKernelGGL(fold_w, dim3(8, 8, 2), dim3(256), 0, stream, wq, wk, wv,
                       scale, shift, Wst2, bias, ctx2);
    hipLaunchKernelGGL(qkv_ctx, dim3(NNTOK / 128 * NHEAD * BB), dim3(256), 0, stream,
                       xn_t, Wst2, bias, qm_t, ctx2);
    hipLaunchKernelGGL(build_A, dim3(8, BB), dim3(256), 0, stream, w_out, ctx2, Amat, ksum);
    hipLaunchKernelGGL(final_out, dim3(NNTOK / 128, 2, BB), dim3(256), 0, stream,
                       qm_t, Amat, ksum, b_out, x, out);
}

// Round 13
// 227.090 us; speedup vs baseline: 1.2604x; 1.1291x over previous
//
#include <hip/hip_runtime.h>
#include <math.h>

#define BB 2
#define CC 256
#define NHEAD 8
#define HD 32
#define NGRP 8
#define NNTOK 32768
#define ATT_EPS 1e-6f
#define GN_EPS 1e-5f

typedef __attribute__((ext_vector_type(8))) short bfrag8;   // 8 bf16
typedef __attribute__((ext_vector_type(4))) float accf4;    // MFMA C/D 16x16

__device__ __forceinline__ float b2f(unsigned short u) {
    unsigned int x = ((unsigned int)u) << 16;
    return __uint_as_float(x);
}
__device__ __forceinline__ unsigned short f2b(float f) {
    unsigned int x = __float_as_uint(f);
    unsigned int r = x + 0x7fffu + ((x >> 16) & 1u);
    return (unsigned short)(r >> 16);
}
__device__ __forceinline__ void gl_lds16(const void* g, void* s) {
    __builtin_amdgcn_global_load_lds(
        (const __attribute__((address_space(1))) unsigned int*)g,
        (__attribute__((address_space(3))) unsigned int*)s, 16, 0, 0);
}

// ---- workspace layout (float offsets) ----
#define WS_QMT   0ull                      // bf16 [B][H][N][32]
#define WS_XNT   (WS_QMT + 8388608ull)     // bf16 [B][N][264] raw-x transpose
#define WS_WSTOLD (WS_XNT + 8650752ull)    // (old region, unused)
#define WS_PART  (WS_WSTOLD + 101632ull)   // big scratch region
#define WS_CTX2  WS_PART                   // f32 [16 bh][1056] atomic accumulators
#define WS_GNP2  (WS_PART + 135168ull)     // f32 [1024 blk][16] GN partials
#define WS_WST2  (WS_PART + 151552ull)     // bf16 [B*H][24576] folded W (frag-linear)
#define WS_BIAS  (WS_PART + 348160ull)     // f32 [B*H][96]
#define WS_GNPO  (WS_PART + 4325376ull)    // old chain (layout stability)
#define WS_SCALE (WS_GNPO + 2048ull)       // f32 [B][256] (unused now)
#define WS_SHIFT (WS_SCALE + 512ull)       // f32 [B][256] (unused now)
#define WS_CTXO  (WS_SHIFT + 512ull)
#define WS_KSUM  (WS_CTXO + 16384ull)      // f32 [B][H][32]
#define WS_AMAT  (WS_KSUM + 512ull)        // bf16 [B][256][256]

// LDS for qkv_ctx (R10-verified): W tile 48KB frag-linear + bias @49152;
// epilogue overlay: kmv 64x272 @0, qs 128x80 @17408, ksp @27648.
// REGISTER CEILING NOTE: this kernel's live state (~84 arch VGPR + 48 acc in
// the unified gfx950 file) fits 3 waves/EU (170 cap) but SPILLS at 4+ (128
// cap) — R11/R12 measured 65-190MB scratch traffic. Do not raise waves/EU.
#define LDS_QS_OFF  17408
#define LDS_KSP_OFF 27648
#define LDS_BIAS_OFF 49152
#define LDS_QKV_TOTAL 49664

// ============ Kernel 1: fused x transpose->bf16 + GN partial sums (R10 verbatim) ============
__global__ __launch_bounds__(256) void xn_gn(const float* __restrict__ x,
                                             unsigned short* __restrict__ xn_t,
                                             float* __restrict__ gnp2) {
    __shared__ unsigned short xt[64][264];   // row = token, 528 B/row
    int b = blockIdx.y, n0 = blockIdx.x * 64, t = threadIdx.x;
    int g16 = t >> 4, ip = t & 15, col4 = ip * 4;
    float gs = 0.f, gs2 = 0.f;
    bfrag8 pk0, pk1, pk2, pk3;
    #pragma unroll
    for (int i = 0; i < 16; ++i) {
        int c = g16 * 16 + i;
        const float4 v = *(const float4*)(x + (size_t)(b * CC + c) * NNTOK + n0 + col4);
        gs  += v.x + v.y + v.z + v.w;
        gs2 += v.x * v.x + v.y * v.y + v.z * v.z + v.w * v.w;
        int k = i & 7;
        pk0[k] = (short)f2b(v.x);
        pk1[k] = (short)f2b(v.y);
        pk2[k] = (short)f2b(v.z);
        pk3[k] = (short)f2b(v.w);
        if (k == 7) {
            int cb = g16 * 32 + (i >> 3) * 16;   // byte offset of channel batch
            char* base = (char*)&xt[0][0] + cb;
            *(bfrag8*)(base + (col4 + 0) * 528) = pk0;
            *(bfrag8*)(base + (col4 + 1) * 528) = pk1;
            *(bfrag8*)(base + (col4 + 2) * 528) = pk2;
            *(bfrag8*)(base + (col4 + 3) * 528) = pk3;
        }
    }
    int lane = t & 63, w = t >> 6;
    #pragma unroll
    for (int off = 16; off; off >>= 1) {
        gs  += __shfl_down(gs, off);
        gs2 += __shfl_down(gs2, off);
    }
    if (lane == 0 || lane == 32) {
        int g = 2 * w + (lane >> 5);
        float* gp = gnp2 + (size_t)(b * 512 + blockIdx.x) * 16;
        gp[g * 2] = gs;
        gp[g * 2 + 1] = gs2;
    }
    __syncthreads();
    int n = t >> 2, q = t & 3;
    const char* src = (const char*)&xt[n][0] + q * 128;
    char* dst = (char*)(xn_t + ((size_t)b * NNTOK + n0 + n) * 264) + q * 128;
    #pragma unroll
    for (int i = 0; i < 8; ++i)
        *(float4*)(dst + i * 16) = *(const float4*)(src + i * 16);
}

// ============ Kernel 2: fold W + bias + ctx2 zero; GN stats computed IN-BLOCK ============
// gn_stats2 launch deleted: each of the 128 blocks redundantly reduces its
// batch's gnp2 (512x16 f32, L2-resident) -> mean/rstd -> sc_l/sh_l.
__global__ __launch_bounds__(256) void fold_w(const float* __restrict__ wq,
                                              const float* __restrict__ wk,
                                              const float* __restrict__ wv,
                                              const float* __restrict__ gnp2,
                                              const float* __restrict__ gamma,
                                              const float* __restrict__ beta,
                                              unsigned short* __restrict__ Wst2,
                                              float* __restrict__ bias,
                                              float* __restrict__ ctx2) {
    int slice = blockIdx.x, h = blockIdx.y, b2 = blockIdx.z, t = threadIdx.x;
    // distributed zero of ctx2 (16*1056 = 16896 floats over 128 blocks)
    {
        int lin = slice + h * 8 + b2 * 64;   // 0..127
        int i = lin * 132 + t;
        if (t < 132) ctx2[i] = 0.f;
    }
    __shared__ float red[256];
    __shared__ float sc_l[256], sh_l[256];
    {
        // stats for this b2: idx = g*2+sel (16), 16 slices of 32 entries
        int sl = t >> 4, idx = t & 15;       // consecutive t -> consecutive idx
        float a = 0.f;
        for (int k = sl; k < 512; k += 16)
            a += gnp2[(size_t)(b2 * 512 + k) * 16 + idx];
        red[sl * 16 + idx] = a;
        __syncthreads();
        if (t < 16) {
            float s = 0.f;
            #pragma unroll
            for (int j2 = 0; j2 < 16; ++j2) s += red[j2 * 16 + t];
            red[t] = s;                      // stats[idx]
        }
        __syncthreads();
        int c = t, g = c >> 5;
        const float inv = 1.0f / (float)((CC / NGRP) * NNTOK);
        float m = red[g * 2] * inv;
        float var = red[g * 2 + 1] * inv - m * m;
        float rstd = rsqrtf(var + GN_EPS);
        float sc = gamma[c] * rstd;
        sc_l[c] = sc;
        sh_l[c] = beta[c] - m * sc;
        __syncthreads();
    }
    const float* Ws[3] = {wq, wk, wv};
    unsigned short* wdst = Wst2 + (size_t)(b2 * NHEAD + h) * 24576;
    for (int i = slice * 3072 + t; i < (slice + 1) * 3072; i += 256) {
        int e = i & 7;
        int chunk = i >> 3;
        int lane = chunk & 63;
        int kcmi = chunk >> 6;
        int mi = kcmi % 6;
        int kc = kcmi / 6;
        int lr = lane & 15, lq = lane >> 4;
        int row = mi * 16 + lr;
        int col = kc * 32 + lq * 8 + e;
        float v = Ws[row >> 5][(size_t)(h * 32 + (row & 31)) * CC + col] * sc_l[col];
        wdst[i] = f2b(v);
    }
    if (t < 96) {
        int rl = t >> 3, sub = t & 7;
        int r = slice * 12 + rl;
        const float* wrow = Ws[r >> 5] + (size_t)(h * 32 + (r & 31)) * CC + sub * 32;
        float sp = 0.f;
        #pragma unroll
        for (int k = 0; k < 8; ++k) {
            const float4 v4 = *(const float4*)(wrow + k * 4);
            const float* shp = &sh_l[sub * 32 + k * 4];
            sp += v4.x * shp[0] + v4.y * shp[1] + v4.z * shp[2] + v4.w * shp[3];
        }
        sp += __shfl_xor(sp, 1);
        sp += __shfl_xor(sp, 2);
        sp += __shfl_xor(sp, 4);
        if (sub == 0) bias[(size_t)(b2 * NHEAD + h) * 96 + r] = sp;
    }
}

// ============ Kernel 3: fused QKV MFMA + bias + elu + ctx/ksum atomics (R10 verbatim) ============
__global__ __launch_bounds__(256, 3) void qkv_ctx(
    const unsigned short* __restrict__ xn_t, const unsigned short* __restrict__ Wst2,
    const float* __restrict__ bias,
    unsigned short* __restrict__ qm_t, float* __restrict__ ctx2) {
    __shared__ char lds[LDS_QKV_TOTAL];
    const int id = blockIdx.x;
    const int xcd = id & 7;
    const int j = id >> 3;
    const int h = j & 7;
    const int rem = j >> 3;                 // 0..63
    const int tile = xcd * 32 + (rem & 31);
    const int b = rem >> 5;
    const int t = threadIdx.x;
    const int lane = t & 63, w = t >> 6;
    const int lr = lane & 15, lq = lane >> 4;
    const int n0 = tile * 128;

    // stage W (48KB) via global_load_lds + bias
    {
        const char* wg = (const char*)(Wst2 + (size_t)(b * NHEAD + h) * 24576);
        for (int jj = w; jj < 48; jj += 4)
            gl_lds16(wg + jj * 1024 + lane * 16, lds + jj * 1024);
        if (t < 96)
            ((float*)(lds + LDS_BIAS_OFF))[t] = bias[(size_t)(b * NHEAD + h) * 96 + t];
    }

    // issue ALL xn fragment loads now — they complete during the stage drain
    const unsigned short* xr0 = xn_t + ((size_t)b * NNTOK + n0 + w * 32 + lr) * 264 + lq * 8;
    const unsigned short* xr1 = xr0 + 16 * 264;
    bfrag8 bnx[8][2];
    #pragma unroll
    for (int kc = 0; kc < 8; ++kc) {
        bnx[kc][0] = *(const bfrag8*)(xr0 + kc * 32);
        bnx[kc][1] = *(const bfrag8*)(xr1 + kc * 32);
    }
    __syncthreads();   // drains gl_lds (and our loads)

    accf4 acc[6][2];
    #pragma unroll
    for (int i = 0; i < 6; ++i)
        #pragma unroll
        for (int jj = 0; jj < 2; ++jj) acc[i][jj] = (accf4){0.f, 0.f, 0.f, 0.f};

    const char* wl = lds;
    bfrag8 wnx[6];
    #pragma unroll
    for (int mi = 0; mi < 6; ++mi)
        wnx[mi] = *(const bfrag8*)(wl + (0 * 6 + mi) * 1024 + lane * 16);

    #pragma unroll
    for (int kc = 0; kc < 8; ++kc) {
        bfrag8 wcur[6];
        #pragma unroll
        for (int mi = 0; mi < 6; ++mi) wcur[mi] = wnx[mi];
        if (kc < 7) {
            #pragma unroll
            for (int mi = 0; mi < 6; ++mi)
                wnx[mi] = *(const bfrag8*)(wl + ((kc + 1) * 6 + mi) * 1024 + lane * 16);
        }
        #pragma unroll
        for (int mi = 0; mi < 6; ++mi)
            #pragma unroll
            for (int ci = 0; ci < 2; ++ci)
                acc[mi][ci] = __builtin_amdgcn_mfma_f32_16x16x32_bf16(wcur[mi], bnx[kc][ci], acc[mi][ci], 0, 0, 0);
    }
    __syncthreads();   // all waves done reading W region — overlay now safe

    const float* biasl = (const float*)(lds + LDS_BIAS_OFF);
    char* kmv = lds;                 // km rows 0..31, v rows 32..63, stride 272
    char* qs  = lds + LDS_QS_OFF;    // qm [n 128][80 B]
    #pragma unroll
    for (int mi = 0; mi < 2; ++mi)
        #pragma unroll
        for (int ci = 0; ci < 2; ++ci)
            #pragma unroll
            for (int r = 0; r < 4; ++r) {
                int d = mi * 16 + lq * 4 + r;
                int n = w * 32 + ci * 16 + lr;
                float q = acc[mi][ci][r] + biasl[d];
                *(unsigned short*)(qs + n * 80 + d * 2) = f2b(q > 0.f ? q + 1.f : __expf(q));
            }
    #pragma unroll
    for (int mi = 2; mi < 4; ++mi)
        #pragma unroll
        for (int ci = 0; ci < 2; ++ci)
            #pragma unroll
            for (int r = 0; r < 4; ++r) {
                int d = (mi - 2) * 16 + lq * 4 + r;
                int n = w * 32 + ci * 16 + lr;
                float kk = acc[mi][ci][r] + biasl[32 + d];
                *(unsigned short*)(kmv + d * 272 + n * 2) = f2b(kk > 0.f ? kk + 1.f : __expf(kk));
            }
    #pragma unroll
    for (int mi = 4; mi < 6; ++mi)
        #pragma unroll
        for (int ci = 0; ci < 2; ++ci)
            #pragma unroll
            for (int r = 0; r < 4; ++r) {
                int e = (mi - 4) * 16 + lq * 4 + r;
                int n = w * 32 + ci * 16 + lr;
                *(unsigned short*)(kmv + (32 + e) * 272 + n * 2) = f2b(acc[mi][ci][r] + biasl[64 + e]);
            }
    __syncthreads();

    float* ctx2p = ctx2 + (size_t)(b * NHEAD + h) * 1056;

    {
        char* qg = (char*)(qm_t + ((size_t)(b * NHEAD + h) * NNTOK + n0) * 32);
        int n = t >> 1, half = t & 1;
        const char* src = qs + n * 80 + half * 32;
        char* dst = qg + n * 64 + half * 32;
        *(float4*)dst = *(const float4*)src;
        *(float4*)(dst + 16) = *(const float4*)(src + 16);
    }

    {
        int qr = w >> 1, qc = w & 1;
        accf4 cacc = (accf4){0.f, 0.f, 0.f, 0.f};
        #pragma unroll
        for (int kk = 0; kk < 4; ++kk) {
            bfrag8 a  = *(const bfrag8*)(kmv + (qr * 16 + lr) * 272 + kk * 64 + lq * 16);
            bfrag8 bb = *(const bfrag8*)(kmv + (32 + qc * 16 + lr) * 272 + kk * 64 + lq * 16);
            cacc = __builtin_amdgcn_mfma_f32_16x16x32_bf16(a, bb, cacc, 0, 0, 0);
        }
        #pragma unroll
        for (int r = 0; r < 4; ++r) {
            int d = qr * 16 + lq * 4 + r, e = qc * 16 + lr;
            atomicAdd(ctx2p + d * 32 + e, cacc[r]);
        }
    }

    {
        float* ksp = (float*)(lds + LDS_KSP_OFF);
        int d = t >> 3, oc = t & 7;
        float s = 0.f;
        for (int i = 0; i < 16; ++i)
            s += b2f(*(const unsigned short*)(kmv + d * 272 + (oc * 16 + i) * 2));
        ksp[d * 8 + oc] = s;
        __syncthreads();
        if (t < 32) {
            float s2 = 0.f;
            #pragma unroll
            for (int i = 0; i < 8; ++i) s2 += ksp[t * 8 + i];
            atomicAdd(ctx2p + 1024 + t, s2);
        }
    }
}

// ============ Kernel 4: build A (bf16) + finalize ksum (R10 verbatim) ============
__global__ __launch_bounds__(256) void build_A(const float* __restrict__ w_out,
                                               const float* __restrict__ ctx2,
                                               unsigned short* __restrict__ Amat,
                                               float* __restrict__ ksum_g) {
    int ot = blockIdx.x, b = blockIdx.y, t = threadIdx.x;
    __shared__ float cs[NHEAD * HD * HD];
    for (int i = t; i < NHEAD * HD * HD; i += 256) {
        int hh = i >> 10, de = i & 1023;
        cs[i] = ctx2[(size_t)(b * NHEAD + hh) * 1056 + de];
    }
    if (ot == 0)
        ksum_g[b * CC + t] = ctx2[(size_t)(b * NHEAD + (t >> 5)) * 1056 + 1024 + (t & 31)];
    __syncthreads();
    int h = t >> 5, d = t & 31;
    for (int oi = 0; oi < 32; ++oi) {
        int o = ot * 32 + oi;
        const float* wrow = w_out + (size_t)o * CC + h * HD;
        float s = 0.f;
        #pragma unroll
        for (int e = 0; e < HD; ++e) s += wrow[e] * cs[h * 1024 + d * 32 + e];
        Amat[((size_t)(b * CC + o)) * CC + t] = f2b(s);
    }
}

// ============ Kernel 5: out = A @ (qm*den) + b_out + x (R6-verified, R10 verbatim) ============
#define LDSF_A   0
#define LDSF_Q   10240
#define LDSF_BO  20480      // 128 f32
#define LDSF_KS  20992      // 256 f32
#define LDSF_TOT 22016
__global__ __launch_bounds__(256, 4) void final_out(
    const unsigned short* __restrict__ qm_t, const unsigned short* __restrict__ Amat,
    const float* __restrict__ ksum_g, const float* __restrict__ b_out,
    const float* __restrict__ x, float* __restrict__ out) {
    __shared__ char L[LDSF_TOT];
    int tile = blockIdx.x, mt = blockIdx.y, b = blockIdx.z;
    int n0 = tile * 128, t = threadIdx.x;
    int lane = t & 63, w = t >> 6, lr = lane & 15, lq = lane >> 4;
    int wm = (w >> 1) * 64, wn = (w & 1) * 64;
    accf4 acc[4][4];
    #pragma unroll
    for (int i = 0; i < 4; ++i)
        #pragma unroll
        for (int j = 0; j < 4; ++j) acc[i][j] = (accf4){0.f, 0.f, 0.f, 0.f};

    if (t < 128) ((float*)(L + LDSF_BO))[t] = b_out[mt * 128 + t];
    ((float*)(L + LDSF_KS))[t] = ksum_g[b * CC + t];

    char* Al = L + LDSF_A;
    char* Ql = L + LDSF_Q;
    const int m = t >> 1, half = t & 1;
    const char* ag = (const char*)(Amat + (size_t)(b * CC + mt * 128 + m) * CC) + half * 32;
    const char* qg = (const char*)(qm_t + ((size_t)b * NHEAD * NNTOK + (size_t)(n0 + m)) * 32) + half * 32;

    bfrag8 a0 = *(const bfrag8*)ag;
    bfrag8 a1 = *(const bfrag8*)(ag + 16);
    bfrag8 q0 = *(const bfrag8*)qg;
    bfrag8 q1 = *(const bfrag8*)(qg + 16);

    __syncthreads();   // ksum/bo visible

    for (int h = 0; h < NHEAD; ++h) {
        const float* ks = (const float*)(L + LDSF_KS) + h * 32 + half * 16;
        float sp = 0.f;
        #pragma unroll
        for (int e = 0; e < 8; ++e) {
            sp += b2f((unsigned short)q0[e]) * ks[e];
            sp += b2f((unsigned short)q1[e]) * ks[8 + e];
        }
        float dot = sp + __shfl_xor(sp, 1);
        float dn = 1.0f / (dot + ATT_EPS);

        __syncthreads();   // previous head's MFMA done reading LDS
        *(bfrag8*)(Al + m * 80 + half * 32) = a0;
        *(bfrag8*)(Al + m * 80 + half * 32 + 16) = a1;
        bfrag8 s0, s1;
        #pragma unroll
        for (int e = 0; e < 8; ++e) {
            s0[e] = (short)f2b(b2f((unsigned short)q0[e]) * dn);
            s1[e] = (short)f2b(b2f((unsigned short)q1[e]) * dn);
        }
        *(bfrag8*)(Ql + m * 80 + half * 32) = s0;
        *(bfrag8*)(Ql + m * 80 + half * 32 + 16) = s1;
        __syncthreads();   // tiles ready

        if (h < 7) {       // prefetch next head during MFMA
            a0 = *(const bfrag8*)(ag + (h + 1) * 64);
            a1 = *(const bfrag8*)(ag + (h + 1) * 64 + 16);
            q0 = *(const bfrag8*)(qg + (size_t)(h + 1) * NNTOK * 64);
            q1 = *(const bfrag8*)(qg + (size_t)(h + 1) * NNTOK * 64 + 16);
        }

        bfrag8 bfr[4];
        #pragma unroll
        for (int ci = 0; ci < 4; ++ci) {
            int n = wn + ci * 16 + lr;
            bfr[ci] = *(const bfrag8*)(Ql + n * 80 + lq * 16);
        }
        #pragma unroll
        for (int mi = 0; mi < 4; ++mi) {
            bfrag8 a = *(const bfrag8*)(Al + (wm + mi * 16 + lr) * 80 + lq * 16);
            #pragma unroll
            for (int ci = 0; ci < 4; ++ci)
                acc[mi][ci] = __builtin_amdgcn_mfma_f32_16x16x32_bf16(a, bfr[ci], acc[mi][ci], 0, 0, 0);
        }
    }

    const float* bo_s = (const float*)(L + LDSF_BO);
    #pragma unroll
    for (int mi = 0; mi < 4; ++mi)
        #pragma unroll
        for (int ci = 0; ci < 4; ++ci)
            #pragma unroll
            for (int r = 0; r < 4; ++r) {
                int ol = wm + mi * 16 + lq * 4 + r;
                int n = wn + ci * 16 + lr;
                size_t idx = ((size_t)(b * CC + mt * 128 + ol)) * NNTOK + n0 + n;
                out[idx] = acc[mi][ci][r] + bo_s[ol] + x[idx];
            }
}

extern "C" void kernel_launch(void* const* d_in, const int* in_sizes, int n_in,
                              void* d_out, int out_size, void* d_ws, size_t ws_size,
                              hipStream_t stream) {
    (void)in_sizes; (void)n_in; (void)out_size; (void)ws_size;
    const float* x      = (const float*)d_in[0];
    const float* gamma  = (const float*)d_in[1];
    const float* beta   = (const float*)d_in[2];
    const float* wq     = (const float*)d_in[3];
    const float* wk     = (const float*)d_in[4];
    const float* wv     = (const float*)d_in[5];
    const float* w_out  = (const float*)d_in[6];
    const float* b_out  = (const float*)d_in[7];
    float* out = (float*)d_out;
    float* ws  = (float*)d_ws;

    unsigned short* qm_t = (unsigned short*)(ws + WS_QMT);
    unsigned short* xn_t = (unsigned short*)(ws + WS_XNT);
    float* ctx2 = ws + WS_CTX2;
    float* gnp2 = ws + WS_GNP2;
    unsigned short* Wst2 = (unsigned short*)(ws + WS_WST2);
    float* bias = ws + WS_BIAS;
    float* ksum = ws + WS_KSUM;
    unsigned short* Amat = (unsigned short*)(ws + WS_AMAT);

    hipLaunchKernelGGL(xn_gn, dim3(NNTOK / 64, BB), dim3(256), 0, stream, x, xn_t, gnp2);
    hipLaunchKernelGGL(fold_w, dim3(8, 8, 2), dim3(256), 0, stream, wq, wk, wv,
                       gnp2, gamma, beta, Wst2, bias, ctx2);
    hipLaunchKernelGGL(qkv_ctx, dim3(NNTOK / 128 * NHEAD * BB), dim3(256), 0, stream,
                       xn_t, Wst2, bias, qm_t, ctx2);
    hipLaunchKernelGGL(build_A, dim3(8, BB), dim3(256), 0, stream, w_out, ctx2, Amat, ksum);
    hipLaunchKernelGGL(final_out, dim3(NNTOK / 128, 2, BB), dim3(256), 0, stream,
                       qm_t, Amat, ksum, b_out, x, out);
}